// Round 1
// baseline (6093.672 us; speedup 1.0000x reference)
//
#include <hip/hip_runtime.h>
#include <math.h>

#define BQ 32
#define TQ 512
#define DQ 768
#define KQ 256
#define HQ 512
#define G4 2048
#define SROW 772   // state row: h[0:512) | key_r[512:769) | pad
#define NWG 256
#define NTHR 256
#define NB 8       // batches per group

typedef float f32x4 __attribute__((ext_vector_type(4)));

__device__ __forceinline__ void waitcnt0() {
  asm volatile("s_waitcnt vmcnt(0) lgkmcnt(0)" ::: "memory");
}
__device__ __forceinline__ void st_agent(float* p, float v) {
  asm volatile("global_store_dword %0, %1, off sc0 sc1" :: "v"(p), "v"(v) : "memory");
}
__device__ __forceinline__ int ld_flag(const int* p) {
  int v;
  asm volatile("global_load_dword %0, %1, off sc0 sc1\ns_waitcnt vmcnt(0)"
               : "=v"(v) : "v"(p) : "memory");
  return v;
}
__device__ __forceinline__ void wg_wait(const int* flags, int target) {
  const int lane = threadIdx.x & 63;
  for (;;) {
    int v = ld_flag(flags + lane);
    if (__all(v >= target)) break;
    __builtin_amdgcn_s_sleep(1);
  }
  __syncthreads();
}
__device__ __forceinline__ void wg_signal(int* flag, int val) {
  waitcnt0();
  __syncthreads();
  if (threadIdx.x == 0)
    asm volatile("global_store_dword %0, %1, off sc0 sc1" :: "v"(flag), "v"(val) : "memory");
}

// ---------------- P1: Gram matrix G[b][t][tau] = x_t . x_tau ----------------
__global__ void __launch_bounds__(256) gram_k(const float* __restrict__ X,
                                              float* __restrict__ Gm) {
  __shared__ __align__(16) float As[64 * 33];
  __shared__ __align__(16) float Bs[64 * 33];
  const int bid = blockIdx.x;
  const int b = blockIdx.y;
  int I = 0, base = 0;
  while (base + I + 1 <= bid) { base += I + 1; ++I; }
  const int J = bid - base;
  const int t0 = I * 64, u0 = J * 64;
  const float* Xb = X + (size_t)b * TQ * DQ;
  const int ty = threadIdx.x >> 4, tx = threadIdx.x & 15;
  const int sc = threadIdx.x & 31, sr = threadIdx.x >> 5;
  float acc[4][4];
#pragma unroll
  for (int i = 0; i < 4; ++i)
#pragma unroll
    for (int j = 0; j < 4; ++j) acc[i][j] = 0.f;
  for (int k0 = 0; k0 < DQ; k0 += 32) {
#pragma unroll
    for (int rr = 0; rr < 8; ++rr) {
      const int r = rr * 8 + sr;
      As[r * 33 + sc] = Xb[(size_t)(t0 + r) * DQ + k0 + sc];
      Bs[r * 33 + sc] = Xb[(size_t)(u0 + r) * DQ + k0 + sc];
    }
    __syncthreads();
#pragma unroll
    for (int k = 0; k < 32; ++k) {
      float av[4], bv[4];
#pragma unroll
      for (int i = 0; i < 4; ++i) av[i] = As[(ty * 4 + i) * 33 + k];
#pragma unroll
      for (int j = 0; j < 4; ++j) bv[j] = Bs[(tx * 4 + j) * 33 + k];
#pragma unroll
      for (int i = 0; i < 4; ++i)
#pragma unroll
        for (int j = 0; j < 4; ++j) acc[i][j] += av[i] * bv[j];
    }
    __syncthreads();
  }
  float* gb = Gm + (size_t)b * TQ * TQ;
#pragma unroll
  for (int i = 0; i < 4; ++i) {
    f32x4 o;
    o.x = acc[i][0]; o.y = acc[i][1]; o.z = acc[i][2]; o.w = acc[i][3];
    *(f32x4*)&gb[(size_t)(t0 + ty * 4 + i) * TQ + u0 + tx * 4] = o;
  }
}

// ---------------- P2: row softmax (tau < t) in place + S[b][t] ----------------
__global__ void __launch_bounds__(256) smax_k(float* __restrict__ Gm,
                                              float* __restrict__ Sv,
                                              const float* __restrict__ cgp,
                                              const float* __restrict__ cbp) {
  const int t = blockIdx.x + 1;   // 1..511
  const int b = blockIdx.y;
  const int tid = threadIdx.x;
  const int lane = tid & 63;
  const int wv = tid >> 6;
  __shared__ float row[TQ];
  __shared__ float r1[4], r2[4], r3[4];
  float* R = Gm + ((size_t)b * TQ + t) * TQ;
  const float cg = cgp[0], cb = cbp[0];
  for (int i = tid; i < t; i += 256) row[i] = R[i];
  __syncthreads();
  float m = -3e38f;
  for (int i = tid; i < t; i += 256) m = fmaxf(m, row[i]);
#pragma unroll
  for (int k = 1; k < 64; k <<= 1) m = fmaxf(m, __shfl_xor(m, k));
  if (lane == 0) r1[wv] = m;
  __syncthreads();
  m = fmaxf(fmaxf(r1[0], r1[1]), fmaxf(r1[2], r1[3]));
  float s = 0.f, sck = 0.f;
  for (int i = tid; i < t; i += 256) {
    const float r = row[i];
    const float e = expf(r - m);
    const float ck = 1.f / (1.f + expf(-(r * cg + cb)));
    row[i] = e; s += e; sck += e * ck;
  }
#pragma unroll
  for (int k = 1; k < 64; k <<= 1) { s += __shfl_xor(s, k); sck += __shfl_xor(sck, k); }
  if (lane == 0) { r2[wv] = s; r3[wv] = sck; }
  __syncthreads();
  s = r2[0] + r2[1] + r2[2] + r2[3];
  sck = r3[0] + r3[1] + r3[2] + r3[3];
  const float inv = 1.f / s;
  for (int i = tid; i < t; i += 256) R[i] = row[i] * inv;
  if (tid == 0) Sv[(size_t)b * TQ + t] = sck * inv;
}

// ---------------- K3: persistent recurrence ----------------
// 4 batch-groups x 64 WGs. WG owns 8 hidden units (32 z-cols, weights in regs)
// and 4 key_r components. Flags in LLC; state via sc0sc1 (agent-coherent) ops.
__global__ void __launch_bounds__(NTHR, 1) esbn_scan(
    const float* __restrict__ Wx, const float* __restrict__ Wh,
    const float* __restrict__ bl, const float* __restrict__ Wk,
    const float* __restrict__ bk, const float* __restrict__ Wg,
    const float* __restrict__ bgp, const float* __restrict__ Wmat,
    float* __restrict__ Mk, const float* __restrict__ Sv,
    float* buf, int* flagsX, int* flagsY, float* __restrict__ out) {
  __shared__ __align__(16) float st[NB * SROW];     // [h | key_r] per local batch
  __shared__ __align__(16) float wrow[NB * TQ];     // softmax row t
  __shared__ float wkey_s[4 * 520];
  __shared__ float wgv[HQ];
  __shared__ __align__(16) float zred[4 * 8 * 8 * 4];
  __shared__ float zfin[NB * 32];
  __shared__ float c_s[NB * 8];
  __shared__ float gg_s[NB];
  __shared__ float A_s[NB * 4];
  __shared__ float bl_s[32];
  __shared__ float bk_s[4];
  __shared__ float bg_s;

  const int tid = threadIdx.x;
  const int wg = blockIdx.x & 63;
  const int grp = blockIdx.x >> 6;
  const int b0 = grp * NB;
  const int dc = tid >> 3;   // d-chunk 0..31
  const int cg = tid & 7;    // col group (4 cols)

  int colg[4];
#pragma unroll
  for (int j = 0; j < 4; ++j) {
    const int c = cg * 4 + j;
    colg[j] = (c >> 3) * HQ + wg * 8 + (c & 7);
  }
  f32x4 wh[16], wxr[8], wxl;
#pragma unroll
  for (int i = 0; i < 16; ++i) {
    const int d = (i << 5) + dc;
    wh[i].x = Wh[(size_t)d * G4 + colg[0]];
    wh[i].y = Wh[(size_t)d * G4 + colg[1]];
    wh[i].z = Wh[(size_t)d * G4 + colg[2]];
    wh[i].w = Wh[(size_t)d * G4 + colg[3]];
  }
#pragma unroll
  for (int i = 0; i < 8; ++i) {
    const int d = (i << 5) + dc;
    wxr[i].x = Wx[(size_t)d * G4 + colg[0]];
    wxr[i].y = Wx[(size_t)d * G4 + colg[1]];
    wxr[i].z = Wx[(size_t)d * G4 + colg[2]];
    wxr[i].w = Wx[(size_t)d * G4 + colg[3]];
  }
  wxl.x = wxl.y = wxl.z = wxl.w = 0.f;
  if (dc == 0) {
    wxl.x = Wx[(size_t)256 * G4 + colg[0]];
    wxl.y = Wx[(size_t)256 * G4 + colg[1]];
    wxl.z = Wx[(size_t)256 * G4 + colg[2]];
    wxl.w = Wx[(size_t)256 * G4 + colg[3]];
  }
  for (int i = tid; i < NB * SROW; i += NTHR) st[i] = 0.f;
  for (int i = tid; i < 4 * 520; i += NTHR) {
    const int kl = i / 520, u = i - kl * 520;
    wkey_s[i] = (u < HQ) ? Wk[(size_t)u * KQ + wg * 4 + kl] : 0.f;
  }
  for (int i = tid; i < HQ; i += NTHR) wgv[i] = Wg[i];
  if (tid < 32) bl_s[tid] = bl[(tid >> 3) * HQ + wg * 8 + (tid & 7)];
  if (tid < 4) bk_s[tid] = bk[wg * 4 + tid];
  if (tid == 0) bg_s = bgp[0];
  if (tid < NB * 8) c_s[tid] = 0.f;
  __syncthreads();

  int* fx = flagsX + grp * 64;
  int* fy = flagsY + grp * 64;
  const int yb = tid >> 5;
  const int ykl = (tid >> 3) & 3;
  const int ytc = tid & 7;

  for (int t = 0; t < TQ; ++t) {
    const int p = t & 1, pn = p ^ 1;
    // ================= X phase =================
    f32x4 acc[8];
#pragma unroll
    for (int b = 0; b < 8; ++b) { acc[b].x = 0.f; acc[b].y = 0.f; acc[b].z = 0.f; acc[b].w = 0.f; }
    // h-part of z (h_{t-1} already in LDS; no wait needed)
#pragma unroll
    for (int i = 0; i < 16; ++i) {
      const f32x4 w = wh[i];
      const int d = (i << 5) + dc;
#pragma unroll
      for (int b = 0; b < 8; ++b) acc[b] += st[b * SROW + d] * w;
    }
    wg_wait(fy, t);   // key_r_t ready (hidden behind the h-part GEMM)
    {  // stage key_r_t (257 + pad = 65 f4 per batch)
      float* base = buf + (size_t)(p * BQ + b0) * SROW;
      const int j0 = tid, j1 = tid + 256;
      const int r0 = j0 / 65, o0 = j0 - r0 * 65;
      const int r1i = j1 / 65, o1 = j1 - r1i * 65;
      const float* q0 = base + r0 * SROW + 512 + (o0 << 2);
      const float* q1 = base + r1i * SROW + 512 + (o1 << 2);
      f32x4 u0, u1, u2;
      u2.x = u2.y = u2.z = u2.w = 0.f;
      asm volatile("global_load_dwordx4 %0, %1, off sc0 sc1" : "=v"(u0) : "v"(q0));
      asm volatile("global_load_dwordx4 %0, %1, off sc0 sc1" : "=v"(u1) : "v"(q1));
      if (tid < 8) {
        const int j2 = tid + 512;
        const int r2i = j2 / 65, o2 = j2 - r2i * 65;
        const float* q2 = base + r2i * SROW + 512 + (o2 << 2);
        asm volatile("global_load_dwordx4 %0, %1, off sc0 sc1" : "=v"(u2) : "v"(q2));
      }
      asm volatile("s_waitcnt vmcnt(0)" : "+v"(u0), "+v"(u1), "+v"(u2) : : "memory");
      *(f32x4*)&st[r0 * SROW + 512 + (o0 << 2)] = u0;
      *(f32x4*)&st[r1i * SROW + 512 + (o1 << 2)] = u1;
      if (tid < 8) {
        const int j2 = tid + 512;
        const int r2i = j2 / 65, o2 = j2 - r2i * 65;
        *(f32x4*)&st[r2i * SROW + 512 + (o2 << 2)] = u2;
      }
    }
    __syncthreads();
#pragma unroll
    for (int i = 0; i < 8; ++i) {
      const f32x4 w = wxr[i];
      const int d = 512 + (i << 5) + dc;
#pragma unroll
      for (int b = 0; b < 8; ++b) acc[b] += st[b * SROW + d] * w;
    }
    if (dc == 0) {
#pragma unroll
      for (int b = 0; b < 8; ++b) acc[b] += st[b * SROW + 768] * wxl;
    }
#pragma unroll
    for (int m = 8; m <= 32; m <<= 1) {
#pragma unroll
      for (int b = 0; b < 8; ++b) {
        acc[b].x += __shfl_xor(acc[b].x, m);
        acc[b].y += __shfl_xor(acc[b].y, m);
        acc[b].z += __shfl_xor(acc[b].z, m);
        acc[b].w += __shfl_xor(acc[b].w, m);
      }
    }
    {
      const int lane = tid & 63;
      if (lane < 8) {
        const int wv = tid >> 6;
#pragma unroll
        for (int b = 0; b < 8; ++b)
          *(f32x4*)&zred[((wv * 8 + lane) * 8 + b) * 4] = acc[b];
      }
    }
    __syncthreads();
    {
      const int b = tid >> 5, c = tid & 31;
      float z = bl_s[c];
#pragma unroll
      for (int wv = 0; wv < 4; ++wv) z += zred[((wv * 8 + (c >> 2)) * 8 + b) * 4 + (c & 3)];
      zfin[b * 32 + c] = z;
    }
    __syncthreads();
    if (tid < 64) {
      const int b = tid >> 3, ul = tid & 7;
      const float zi = zfin[b * 32 + ul];
      const float zf = zfin[b * 32 + 8 + ul];
      const float zc = zfin[b * 32 + 16 + ul];
      const float zo = zfin[b * 32 + 24 + ul];
      const float gi = 1.f / (1.f + expf(-zi));
      const float gf = 1.f / (1.f + expf(-zf));
      const float go = 1.f / (1.f + expf(-zo));
      const float cn = gf * c_s[tid] + gi * tanhf(zc);
      const float hv = go * tanhf(cn);
      c_s[tid] = cn;
      st_agent(buf + (size_t)(pn * BQ + b0 + b) * SROW + wg * 8 + ul, hv);
      if (t == TQ - 1) out[(size_t)(b0 + b) * HQ + wg * 8 + ul] = hv;
    }
    wg_signal(&fx[wg], t + 1);
    if (t == TQ - 1) break;

    // ================= Y phase =================
    if (t > 0) {  // stage softmax row t (before waiting for h_t)
      const int nf4 = (t + 3) >> 2;
      const float* wr = Wmat + ((size_t)(b0 + yb) * TQ + t) * TQ;
      for (int o = (tid & 31); o < nf4; o += 32)
        *(f32x4*)&wrow[yb * TQ + (o << 2)] = *(const f32x4*)&wr[o << 2];
    }
    __syncthreads();
    float accA = 0.f;
    if (t > 0) {  // A[b][k] = sum_{tau<t} w[tau]*Mk[tau]  (WG-private Mk slice)
      const float* mk = Mk + ((size_t)(b0 + yb) * KQ + wg * 4 + ykl) * TQ;
      const float* wb = &wrow[yb * TQ];
#pragma unroll 4
      for (int u = ytc; u < t; u += 8) accA += wb[u] * mk[u];
      accA += __shfl_xor(accA, 1);
      accA += __shfl_xor(accA, 2);
      accA += __shfl_xor(accA, 4);
    }
    if (ytc == 0) A_s[yb * 4 + ykl] = accA;
    wg_wait(fx, t + 1);   // h_t ready
    {  // stage h_t
      float* base = buf + (size_t)(pn * BQ + b0) * SROW;
      f32x4 v0, v1, v2, v3;
      const int i0 = tid, i1 = tid + 256, i2 = tid + 512, i3 = tid + 768;
      const float* p0 = base + (i0 >> 7) * SROW + ((i0 & 127) << 2);
      const float* p1v = base + (i1 >> 7) * SROW + ((i1 & 127) << 2);
      const float* p2v = base + (i2 >> 7) * SROW + ((i2 & 127) << 2);
      const float* p3v = base + (i3 >> 7) * SROW + ((i3 & 127) << 2);
      asm volatile("global_load_dwordx4 %0, %1, off sc0 sc1" : "=v"(v0) : "v"(p0));
      asm volatile("global_load_dwordx4 %0, %1, off sc0 sc1" : "=v"(v1) : "v"(p1v));
      asm volatile("global_load_dwordx4 %0, %1, off sc0 sc1" : "=v"(v2) : "v"(p2v));
      asm volatile("global_load_dwordx4 %0, %1, off sc0 sc1" : "=v"(v3) : "v"(p3v));
      asm volatile("s_waitcnt vmcnt(0)" : "+v"(v0), "+v"(v1), "+v"(v2), "+v"(v3) : : "memory");
      *(f32x4*)&st[(i0 >> 7) * SROW + ((i0 & 127) << 2)] = v0;
      *(f32x4*)&st[(i1 >> 7) * SROW + ((i1 & 127) << 2)] = v1;
      *(f32x4*)&st[(i2 >> 7) * SROW + ((i2 & 127) << 2)] = v2;
      *(f32x4*)&st[(i3 >> 7) * SROW + ((i3 & 127) << 2)] = v3;
    }
    __syncthreads();
    {  // g[b] = sigmoid(h . Wg + bg)
      const int b = tid >> 5, uc = tid & 31;
      float a = 0.f;
      for (int u = uc; u < HQ; u += 32) a += st[b * SROW + u] * wgv[u];
#pragma unroll
      for (int m = 1; m <= 16; m <<= 1) a += __shfl_xor(a, m);
      if (uc == 0) gg_s[b] = 1.f / (1.f + expf(-(a + bg_s)));
    }
    float kw = 0.f;
    {  // key_w[b][k] = h . Wkey[:,k]
      const float* hrow = &st[yb * SROW];
      const float* wkr = &wkey_s[ykl * 520];
#pragma unroll 4
      for (int u = ytc; u < HQ; u += 8) kw += hrow[u] * wkr[u];
      kw += __shfl_xor(kw, 1);
      kw += __shfl_xor(kw, 2);
      kw += __shfl_xor(kw, 4);
    }
    __syncthreads();
    if (ytc == 0) {
      Mk[((size_t)(b0 + yb) * KQ + wg * 4 + ykl) * TQ + t] = kw + bk_s[ykl];
      st_agent(buf + (size_t)(pn * BQ + b0 + yb) * SROW + 512 + wg * 4 + ykl,
               gg_s[yb] * A_s[yb * 4 + ykl]);
    }
    if (wg == 63 && (tid & 31) == 0) {  // key_r component 256 = g * S[b][t]
      const int b = tid >> 5;
      st_agent(buf + (size_t)(pn * BQ + b0 + b) * SROW + 512 + 256,
               gg_s[b] * Sv[(size_t)(b0 + b) * TQ + t]);
    }
    wg_signal(&fy[wg], t + 1);
  }
}

extern "C" void kernel_launch(void* const* d_in, const int* in_sizes, int n_in,
                              void* d_out, int out_size, void* d_ws, size_t ws_size,
                              hipStream_t stream) {
  (void)in_sizes; (void)n_in; (void)out_size; (void)ws_size;
  const float* X  = (const float*)d_in[0];
  const float* Wx = (const float*)d_in[1];
  const float* Wh = (const float*)d_in[2];
  const float* bl = (const float*)d_in[3];
  const float* Wk = (const float*)d_in[4];
  const float* bk = (const float*)d_in[5];
  const float* Wg = (const float*)d_in[6];
  const float* bg = (const float*)d_in[7];
  const float* cg = (const float*)d_in[8];
  const float* cb = (const float*)d_in[9];
  float* out = (float*)d_out;
  float* ws = (float*)d_ws;

  float* Gm = ws;                               // 32*512*512 = 8,388,608 f
  float* Mk = ws + (size_t)8388608;             // 32*256*512 = 4,194,304 f
  float* Sv = ws + (size_t)12582912;            // 32*512 = 16,384 f
  float* buf = ws + (size_t)12599296;           // 2*32*772 = 49,408 f
  int* flagsX = (int*)(ws + (size_t)12648704);  // 256 + 256 ints
  int* flagsY = flagsX + 256;

  // zero S | state double-buffer | flags (one contiguous region)
  hipMemsetAsync(Sv, 0, (size_t)(16384 + 49408 + 512) * 4, stream);
  gram_k<<<dim3(36, BQ), dim3(256), 0, stream>>>(X, Gm);
  smax_k<<<dim3(TQ - 1, BQ), dim3(256), 0, stream>>>(Gm, Sv, cg, cb);

  void* args[] = {(void*)&Wx, (void*)&Wh, (void*)&bl, (void*)&Wk, (void*)&bk,
                  (void*)&Wg, (void*)&bg, (void*)&Gm, (void*)&Mk, (void*)&Sv,
                  (void*)&buf, (void*)&flagsX, (void*)&flagsY, (void*)&out};
  hipError_t e = hipLaunchCooperativeKernel((const void*)esbn_scan, dim3(NWG),
                                            dim3(NTHR), args, 0, stream);
  if (e != hipSuccess) {
    // fallback: 256 WGs @ 57KB LDS / 256 thr fit 1/CU on 256 CUs -> co-resident
    esbn_scan<<<dim3(NWG), dim3(NTHR), 0, stream>>>(Wx, Wh, bl, Wk, bk, Wg, bg,
                                                    Gm, Mk, Sv, buf, flagsX,
                                                    flagsY, out);
  }
}

// Round 2
// 4875.797 us; speedup vs baseline: 1.2498x; 1.2498x over previous
//
#include <hip/hip_runtime.h>
#include <math.h>

#define BQ 32
#define TQ 512
#define DQ 768
#define KQ 256
#define HQ 512
#define G4 2048
#define SROW 772   // state row: h[0:512) | key_r[512:769) | pad to 772
#define NWG 512    // 8 groups x 64 WGs
#define NTHR 256
#define NBG 4      // batches per group

typedef float f32x4 __attribute__((ext_vector_type(4)));

__device__ __forceinline__ void waitcnt0() {
  asm volatile("s_waitcnt vmcnt(0) lgkmcnt(0)" ::: "memory");
}
__device__ __forceinline__ void st_agent(float* p, float v) {
  asm volatile("global_store_dword %0, %1, off sc0 sc1" :: "v"(p), "v"(v) : "memory");
}
__device__ __forceinline__ int ld_flag(const int* p) {
  int v;
  asm volatile("global_load_dword %0, %1, off sc0 sc1\ns_waitcnt vmcnt(0)"
               : "=v"(v) : "v"(p) : "memory");
  return v;
}
__device__ __forceinline__ void wg_wait(const int* flags, int target) {
  const int lane = threadIdx.x & 63;
  for (;;) {
    int v = ld_flag(flags + lane);
    if (__all(v >= target)) break;
    __builtin_amdgcn_s_sleep(1);
  }
  __syncthreads();
}
__device__ __forceinline__ void wg_signal(int* flag, int val) {
  waitcnt0();
  __syncthreads();
  if (threadIdx.x == 0)
    asm volatile("global_store_dword %0, %1, off sc0 sc1" :: "v"(flag), "v"(val) : "memory");
}
__device__ __forceinline__ float sigm(float x) { return 1.f / (1.f + __expf(-x)); }

// ---------------- P1: Gram matrix G[b][t][tau] = x_t . x_tau ----------------
__global__ void __launch_bounds__(256) gram_k(const float* __restrict__ X,
                                              float* __restrict__ Gm) {
  __shared__ __align__(16) float As[64 * 33];
  __shared__ __align__(16) float Bs[64 * 33];
  const int bid = blockIdx.x;
  const int b = blockIdx.y;
  int I = 0, base = 0;
  while (base + I + 1 <= bid) { base += I + 1; ++I; }
  const int J = bid - base;
  const int t0 = I * 64, u0 = J * 64;
  const float* Xb = X + (size_t)b * TQ * DQ;
  const int ty = threadIdx.x >> 4, tx = threadIdx.x & 15;
  const int sc = threadIdx.x & 31, sr = threadIdx.x >> 5;
  float acc[4][4];
#pragma unroll
  for (int i = 0; i < 4; ++i)
#pragma unroll
    for (int j = 0; j < 4; ++j) acc[i][j] = 0.f;
  for (int k0 = 0; k0 < DQ; k0 += 32) {
#pragma unroll
    for (int rr = 0; rr < 8; ++rr) {
      const int r = rr * 8 + sr;
      As[r * 33 + sc] = Xb[(size_t)(t0 + r) * DQ + k0 + sc];
      Bs[r * 33 + sc] = Xb[(size_t)(u0 + r) * DQ + k0 + sc];
    }
    __syncthreads();
#pragma unroll
    for (int k = 0; k < 32; ++k) {
      float av[4], bv[4];
#pragma unroll
      for (int i = 0; i < 4; ++i) av[i] = As[(ty * 4 + i) * 33 + k];
#pragma unroll
      for (int j = 0; j < 4; ++j) bv[j] = Bs[(tx * 4 + j) * 33 + k];
#pragma unroll
      for (int i = 0; i < 4; ++i)
#pragma unroll
        for (int j = 0; j < 4; ++j) acc[i][j] += av[i] * bv[j];
    }
    __syncthreads();
  }
  float* gb = Gm + (size_t)b * TQ * TQ;
#pragma unroll
  for (int i = 0; i < 4; ++i) {
    f32x4 o;
    o.x = acc[i][0]; o.y = acc[i][1]; o.z = acc[i][2]; o.w = acc[i][3];
    *(f32x4*)&gb[(size_t)(t0 + ty * 4 + i) * TQ + u0 + tx * 4] = o;
  }
}

// ---------------- P2: row softmax (tau < t) in place + S[b][t] ----------------
__global__ void __launch_bounds__(256) smax_k(float* __restrict__ Gm,
                                              float* __restrict__ Sv,
                                              const float* __restrict__ cgp,
                                              const float* __restrict__ cbp) {
  const int t = blockIdx.x + 1;   // 1..511
  const int b = blockIdx.y;
  const int tid = threadIdx.x;
  const int lane = tid & 63;
  const int wv = tid >> 6;
  __shared__ float row[TQ];
  __shared__ float r1[4], r2[4], r3[4];
  float* R = Gm + ((size_t)b * TQ + t) * TQ;
  const float cg = cgp[0], cb = cbp[0];
  for (int i = tid; i < t; i += 256) row[i] = R[i];
  __syncthreads();
  float m = -3e38f;
  for (int i = tid; i < t; i += 256) m = fmaxf(m, row[i]);
#pragma unroll
  for (int k = 1; k < 64; k <<= 1) m = fmaxf(m, __shfl_xor(m, k));
  if (lane == 0) r1[wv] = m;
  __syncthreads();
  m = fmaxf(fmaxf(r1[0], r1[1]), fmaxf(r1[2], r1[3]));
  float s = 0.f, sck = 0.f;
  for (int i = tid; i < t; i += 256) {
    const float r = row[i];
    const float e = __expf(r - m);
    const float ck = 1.f / (1.f + __expf(-(r * cg + cb)));
    row[i] = e; s += e; sck += e * ck;
  }
#pragma unroll
  for (int k = 1; k < 64; k <<= 1) { s += __shfl_xor(s, k); sck += __shfl_xor(sck, k); }
  if (lane == 0) { r2[wv] = s; r3[wv] = sck; }
  __syncthreads();
  s = r2[0] + r2[1] + r2[2] + r2[3];
  sck = r3[0] + r3[1] + r3[2] + r3[3];
  const float inv = 1.f / s;
  for (int i = tid; i < t; i += 256) R[i] = row[i] * inv;
  if (tid == 0) Sv[(size_t)b * TQ + t] = sck * inv;
}

// ---------------- K3: persistent recurrence ----------------
// 8 groups (4 batches each) x 64 WGs x 256 thr = 512 WGs, 2 WGs/CU.
// WG owns 8 hidden units (32 z-cols, weights in regs) + 4 key components.
// Mk slice lives in LDS; flags + state exchange via LLC (sc0 sc1).
__global__ void __launch_bounds__(NTHR, 2) esbn_scan(
    const float* __restrict__ Wx, const float* __restrict__ Wh,
    const float* __restrict__ bl, const float* __restrict__ Wk,
    const float* __restrict__ bk, const float* __restrict__ Wg,
    const float* __restrict__ bgp, const float* __restrict__ Wmat,
    const float* __restrict__ Sv, float* buf, int* flagsX, int* flagsY,
    float* __restrict__ out) {
  __shared__ __align__(16) float st[NBG * SROW];     // [h | key_r] per local batch
  __shared__ __align__(16) float wrow[NBG * TQ];     // softmax row t (zero-padded)
  __shared__ __align__(16) float Mk_s[16 * 520];     // [b][kl][tau] WG-local key mem
  __shared__ __align__(16) float wkey_s[4 * 520];
  __shared__ float wgv[HQ];
  __shared__ __align__(16) float zred[4 * 8 * 4 * 4];
  __shared__ float c_s[NBG * 8];
  __shared__ float gg_s[NBG];
  __shared__ float A_s[NBG * 4];
  __shared__ float bl_s[32];
  __shared__ float bk_s[4];
  __shared__ float bg_s;

  const int tid = threadIdx.x;
  const int wg = blockIdx.x & 63;
  const int grp = blockIdx.x >> 6;   // 0..7
  const int b0 = grp * NBG;
  const int dc = tid >> 3;   // d-chunk 0..31
  const int cg = tid & 7;    // col group (4 cols)

  int colg[4];
#pragma unroll
  for (int j = 0; j < 4; ++j) {
    const int c = cg * 4 + j;
    colg[j] = (c >> 3) * HQ + wg * 8 + (c & 7);
  }
  f32x4 wh[16], wxr[8], wxl;
#pragma unroll
  for (int i = 0; i < 16; ++i) {
    const int d = (i << 5) + dc;
    wh[i].x = Wh[(size_t)d * G4 + colg[0]];
    wh[i].y = Wh[(size_t)d * G4 + colg[1]];
    wh[i].z = Wh[(size_t)d * G4 + colg[2]];
    wh[i].w = Wh[(size_t)d * G4 + colg[3]];
  }
#pragma unroll
  for (int i = 0; i < 8; ++i) {
    const int d = (i << 5) + dc;
    wxr[i].x = Wx[(size_t)d * G4 + colg[0]];
    wxr[i].y = Wx[(size_t)d * G4 + colg[1]];
    wxr[i].z = Wx[(size_t)d * G4 + colg[2]];
    wxr[i].w = Wx[(size_t)d * G4 + colg[3]];
  }
  wxl.x = wxl.y = wxl.z = wxl.w = 0.f;
  if (dc == 0) {
    wxl.x = Wx[(size_t)256 * G4 + colg[0]];
    wxl.y = Wx[(size_t)256 * G4 + colg[1]];
    wxl.z = Wx[(size_t)256 * G4 + colg[2]];
    wxl.w = Wx[(size_t)256 * G4 + colg[3]];
  }
  for (int i = tid; i < NBG * SROW; i += NTHR) st[i] = 0.f;
  for (int i = tid; i < 16 * 520; i += NTHR) Mk_s[i] = 0.f;
  for (int i = tid; i < 4 * 520; i += NTHR) {
    const int kl = i / 520, u = i - kl * 520;
    wkey_s[i] = (u < HQ) ? Wk[(size_t)u * KQ + wg * 4 + kl] : 0.f;
  }
  for (int i = tid; i < HQ; i += NTHR) wgv[i] = Wg[i];
  if (tid < 32) bl_s[tid] = bl[(tid >> 3) * HQ + wg * 8 + (tid & 7)];
  if (tid < 4) bk_s[tid] = bk[wg * 4 + tid];
  if (tid == 0) bg_s = bgp[0];
  if (tid < NBG * 8) c_s[tid] = 0.f;
  if (tid < NBG * 4) A_s[tid] = 0.f;
  __syncthreads();

  int* fx = flagsX + grp * 64;
  int* fy = flagsY + grp * 64;
  const int yb = tid >> 6;          // batch 0..3
  const int ykl = (tid >> 4) & 3;   // key lane 0..3
  const int ytc = tid & 15;         // tau/u chunk 0..15
  const int lt = tid & 63;

  for (int t = 0; t < TQ; ++t) {
    const int p = t & 1, pn = p ^ 1;
    // ================= X phase =================
    f32x4 acc[NBG];
#pragma unroll
    for (int b = 0; b < NBG; ++b) { acc[b].x = 0.f; acc[b].y = 0.f; acc[b].z = 0.f; acc[b].w = 0.f; }
    // h-part of z (h_{t-1} already staged in LDS)
#pragma unroll
    for (int i = 0; i < 16; ++i) {
      const f32x4 w = wh[i];
      const int d = (i << 5) + dc;
#pragma unroll
      for (int b = 0; b < NBG; ++b) acc[b] += st[b * SROW + d] * w;
    }
    wg_wait(fy, t);   // key_r_t ready (detect hidden behind h-GEMM)
    {  // stage key_r_t: 4 batches x 65 f4
      float* base = buf + (size_t)(p * BQ + b0) * SROW;
      const int r0 = tid / 65, o0 = tid - r0 * 65;
      const float* q0 = base + r0 * SROW + 512 + (o0 << 2);
      f32x4 u0, u1;
      u1.x = u1.y = u1.z = u1.w = 0.f;
      asm volatile("global_load_dwordx4 %0, %1, off sc0 sc1" : "=v"(u0) : "v"(q0));
      if (tid < 4) {
        const int j1 = tid + 256;
        const int r1 = j1 / 65, o1 = j1 - r1 * 65;
        const float* q1 = base + r1 * SROW + 512 + (o1 << 2);
        asm volatile("global_load_dwordx4 %0, %1, off sc0 sc1" : "=v"(u1) : "v"(q1));
      }
      asm volatile("s_waitcnt vmcnt(0)" : "+v"(u0), "+v"(u1) : : "memory");
      *(f32x4*)&st[r0 * SROW + 512 + (o0 << 2)] = u0;
      if (tid < 4) {
        const int j1 = tid + 256;
        const int r1 = j1 / 65, o1 = j1 - r1 * 65;
        *(f32x4*)&st[r1 * SROW + 512 + (o1 << 2)] = u1;
      }
    }
    __syncthreads();
#pragma unroll
    for (int i = 0; i < 8; ++i) {
      const f32x4 w = wxr[i];
      const int d = 512 + (i << 5) + dc;
#pragma unroll
      for (int b = 0; b < NBG; ++b) acc[b] += st[b * SROW + d] * w;
    }
    if (dc == 0) {
#pragma unroll
      for (int b = 0; b < NBG; ++b) acc[b] += st[b * SROW + 768] * wxl;
    }
#pragma unroll
    for (int m = 8; m <= 32; m <<= 1) {
#pragma unroll
      for (int b = 0; b < NBG; ++b) {
        acc[b].x += __shfl_xor(acc[b].x, m);
        acc[b].y += __shfl_xor(acc[b].y, m);
        acc[b].z += __shfl_xor(acc[b].z, m);
        acc[b].w += __shfl_xor(acc[b].w, m);
      }
    }
    if (lt < 8) {
      const int wv = tid >> 6;
#pragma unroll
      for (int b = 0; b < NBG; ++b)
        *(f32x4*)&zred[((wv * 8 + lt) * 4 + b) * 4] = acc[b];
    }
    __syncthreads();
    if (tid < 32) {   // LSTM pointwise: thread = (b,u)
      const int b = tid >> 3, u = tid & 7;
      float zg[4];
#pragma unroll
      for (int g = 0; g < 4; ++g) {
        const int cgi = g * 2 + (u >> 2), comp = u & 3;
        float z = bl_s[g * 8 + u];
#pragma unroll
        for (int wv = 0; wv < 4; ++wv) z += zred[((wv * 8 + cgi) * 4 + b) * 4 + comp];
        zg[g] = z;
      }
      const float gi = sigm(zg[0]);
      const float gf = sigm(zg[1]);
      const float go = sigm(zg[3]);
      const float cn = gf * c_s[tid] + gi * tanhf(zg[2]);
      const float hv = go * tanhf(cn);
      c_s[tid] = cn;
      st_agent(buf + (size_t)(pn * BQ + b0 + b) * SROW + wg * 8 + u, hv);
      if (t == TQ - 1) out[(size_t)(b0 + b) * HQ + wg * 8 + u] = hv;
    }
    wg_signal(&fx[wg], t + 1);
    if (t == TQ - 1) break;

    // ================= Y phase =================
    if (t > 0) {  // stage softmax row t, zero-padded past t
      const float* wr = Wmat + ((size_t)(b0 + yb) * TQ + t) * TQ;
#pragma unroll
      for (int k = 0; k < 8; ++k) {
        const int u = lt + (k << 6);
        wrow[yb * TQ + u] = (u < t) ? wr[u] : 0.f;
      }
    }
    __syncthreads();
    float accA = 0.f;
    if (t > 0) {  // A[b][k] = sum_tau w[tau]*Mk[tau] — fixed 32-iter LDS loop
      const float* mk = &Mk_s[(yb * 4 + ykl) * 520];
      const float* wb = &wrow[yb * TQ];
#pragma unroll
      for (int j = 0; j < 32; ++j) {
        const int u = ytc + (j << 4);
        accA += wb[u] * mk[u];
      }
      accA += __shfl_xor(accA, 1);
      accA += __shfl_xor(accA, 2);
      accA += __shfl_xor(accA, 4);
      accA += __shfl_xor(accA, 8);
    }
    if (ytc == 0) A_s[yb * 4 + ykl] = accA;
    wg_wait(fx, t + 1);   // h_t ready
    {  // stage h_t: 4 batches x 128 f4
      float* base = buf + (size_t)(pn * BQ + b0) * SROW;
      f32x4 v0, v1;
      const int i0 = tid, i1 = tid + 256;
      const float* p0 = base + (i0 >> 7) * SROW + ((i0 & 127) << 2);
      const float* p1v = base + (i1 >> 7) * SROW + ((i1 & 127) << 2);
      asm volatile("global_load_dwordx4 %0, %1, off sc0 sc1" : "=v"(v0) : "v"(p0));
      asm volatile("global_load_dwordx4 %0, %1, off sc0 sc1" : "=v"(v1) : "v"(p1v));
      asm volatile("s_waitcnt vmcnt(0)" : "+v"(v0), "+v"(v1) : : "memory");
      *(f32x4*)&st[(i0 >> 7) * SROW + ((i0 & 127) << 2)] = v0;
      *(f32x4*)&st[(i1 >> 7) * SROW + ((i1 & 127) << 2)] = v1;
    }
    __syncthreads();
    {  // g[b] = sigmoid(h . Wg + bg): 64 lanes per batch
      float a = 0.f;
#pragma unroll
      for (int k = 0; k < 8; ++k) {
        const int u = lt + (k << 6);
        a += st[yb * SROW + u] * wgv[u];
      }
#pragma unroll
      for (int m = 1; m <= 32; m <<= 1) a += __shfl_xor(a, m);
      if (lt == 0) gg_s[yb] = sigm(a + bg_s);
    }
    __syncthreads();
    if (ytc == 0)
      st_agent(buf + (size_t)(pn * BQ + b0 + yb) * SROW + 512 + wg * 4 + ykl,
               gg_s[yb] * A_s[yb * 4 + ykl]);
    if (wg == 63 && lt == 0)   // key_r component 256 = g * S[b][t]
      st_agent(buf + (size_t)(pn * BQ + b0 + yb) * SROW + 512 + 256,
               gg_s[yb] * Sv[(size_t)(b0 + yb) * TQ + t]);
    wg_signal(&fy[wg], t + 1);
    {  // key_w (one step of slack: only needed by next A-dot) -> Mk_s[t]
      float kw = 0.f;
      const float* hrow = &st[yb * SROW];
      const float* wkr = &wkey_s[ykl * 520];
#pragma unroll
      for (int j = 0; j < 32; ++j) {
        const int u = ytc + (j << 4);
        kw += hrow[u] * wkr[u];
      }
      kw += __shfl_xor(kw, 1);
      kw += __shfl_xor(kw, 2);
      kw += __shfl_xor(kw, 4);
      kw += __shfl_xor(kw, 8);
      if (ytc == 0) Mk_s[(yb * 4 + ykl) * 520 + t] = kw + bk_s[ykl];
    }
  }
}

extern "C" void kernel_launch(void* const* d_in, const int* in_sizes, int n_in,
                              void* d_out, int out_size, void* d_ws, size_t ws_size,
                              hipStream_t stream) {
  (void)in_sizes; (void)n_in; (void)out_size; (void)ws_size;
  const float* X  = (const float*)d_in[0];
  const float* Wx = (const float*)d_in[1];
  const float* Wh = (const float*)d_in[2];
  const float* bl = (const float*)d_in[3];
  const float* Wk = (const float*)d_in[4];
  const float* bk = (const float*)d_in[5];
  const float* Wg = (const float*)d_in[6];
  const float* bg = (const float*)d_in[7];
  const float* cg = (const float*)d_in[8];
  const float* cb = (const float*)d_in[9];
  float* out = (float*)d_out;
  float* ws = (float*)d_ws;

  float* Gm = ws;                              // 32*512*512 = 8,388,608 f
  float* Sv = ws + (size_t)8388608;            // 32*512 = 16,384 f
  float* buf = ws + (size_t)8404992;           // 2*32*772 = 49,408 f
  int* flagsX = (int*)(ws + (size_t)8454400);  // 512 + 512 ints
  int* flagsY = flagsX + 512;

  // zero Sv | state double-buffer | flags (one contiguous region)
  hipMemsetAsync(Sv, 0, (size_t)(16384 + 49408 + 1024) * 4, stream);
  gram_k<<<dim3(36, BQ), dim3(256), 0, stream>>>(X, Gm);
  smax_k<<<dim3(TQ - 1, BQ), dim3(256), 0, stream>>>(Gm, Sv, cg, cb);

  void* args[] = {(void*)&Wx, (void*)&Wh, (void*)&bl, (void*)&Wk, (void*)&bk,
                  (void*)&Wg, (void*)&bg, (void*)&Gm, (void*)&Sv,
                  (void*)&buf, (void*)&flagsX, (void*)&flagsY, (void*)&out};
  hipError_t e = hipLaunchCooperativeKernel((const void*)esbn_scan, dim3(NWG),
                                            dim3(NTHR), args, 0, stream);
  if (e != hipSuccess) {
    esbn_scan<<<dim3(NWG), dim3(NTHR), 0, stream>>>(Wx, Wh, bl, Wk, bk, Wg, bg,
                                                    Gm, Sv, buf, flagsX,
                                                    flagsY, out);
  }
}